// Round 15
// baseline (220.269 us; speedup 1.0000x reference)
//
#include <hip/hip_runtime.h>
#include <hip/hip_bf16.h>
#include <hip/hip_fp16.h>

// ---------------- workspace layout (u32 words) ----------------
// g     [256]   f32 (atomic accum, memset 0)
// scal  [2]     f32 (ssq, sasn) (atomic accum, memset 0)
// hd    [256]   int dst-bucket histogram (memset 0)
// hs    [256]   int src-bucket histogram (memset 0)
// offd  [257], offs [257], cd [256], cs [256]  (written by k_prefix)
// ninfo [N*8]   f32 {xs0..xs4, cnt, deg, dis}
// csc   [N]     f32 = dis * inv_l / 15
// keys  [E]     u32 (src<<16 | dst)  -- requires N <= 65536 (N=50000)
// bdw   [E]     uint2 {key, f32 w} dst-binned records
// bs    [E]     u32 src-binned {h16(ew)<<16 | src&0xff}
// Sq    [N*32]  u32 = 256 uint4-vals/node (q=rint(exp(m-mx)*15), permuted)
// pooled[32768] f32
// parts [nparts*16384 u32] (lane-interleaved bf16 pairs)
//   NOTE: k_consume's partial buffer (784*2048 u32 = 6.4MB) ALIASES parts:
//   consume+finalize complete before k_node writes parts (same stream).

#define PR 256
#define NBMAX 256
#define SCH 2048
#define SPLIT 4

typedef _Float16 f16x8 __attribute__((ext_vector_type(8)));
typedef float f32x4 __attribute__((ext_vector_type(4)));

__device__ inline int udot8(uint32_t a, uint32_t b, int c) {
#if __has_builtin(__builtin_amdgcn_udot8)
    return __builtin_amdgcn_udot8(a, b, c, false);
#else
    #pragma unroll
    for (int i = 0; i < 8; i++)
        c += (int)((a >> (4 * i)) & 15) * (int)((b >> (4 * i)) & 15);
    return c;
#endif
}

// ---------------- Kernel H: pack keys + global bucket histogram ---
__launch_bounds__(1024)
__global__ void k_hist(const int* __restrict__ ei, uint32_t* __restrict__ keys,
                       int* __restrict__ hd, int* __restrict__ hs, int E) {
    __shared__ int lhd[NBMAX], lhs[NBMAX];
    int t = threadIdx.x;
    if (t < NBMAX) { lhd[t] = 0; lhs[t] = 0; }
    __syncthreads();
    int idx = blockIdx.x * blockDim.x + t;
    int stride = gridDim.x * blockDim.x;
    for (int e = idx; e < E; e += stride) {
        uint32_t s = (uint32_t)ei[e];
        uint32_t d = (uint32_t)ei[E + e];
        keys[e] = (s << 16) | d;
        atomicAdd(&lhd[d >> 8], 1);
        atomicAdd(&lhs[s >> 8], 1);
    }
    __syncthreads();
    if (t < NBMAX) {
        if (lhd[t]) atomicAdd(&hd[t], lhd[t]);
        if (lhs[t]) atomicAdd(&hs[t], lhs[t]);
    }
}

// ---------------- Kernel X: parallel exclusive prefix -------------
__launch_bounds__(NBMAX)
__global__ void k_prefix(const int* __restrict__ hd, const int* __restrict__ hs,
                         int* __restrict__ offd, int* __restrict__ offs,
                         int* __restrict__ cd, int* __restrict__ cs, int NB) {
    __shared__ int sd[NBMAX], ss[NBMAX];
    int t = threadIdx.x;
    sd[t] = (t < NB) ? hd[t] : 0;
    ss[t] = (t < NB) ? hs[t] : 0;
    __syncthreads();
    #pragma unroll
    for (int o = 1; o < NBMAX; o <<= 1) {
        int vd = (t >= o) ? sd[t - o] : 0;
        int vs = (t >= o) ? ss[t - o] : 0;
        __syncthreads();
        sd[t] += vd; ss[t] += vs;
        __syncthreads();
    }
    int ed = (t == 0) ? 0 : sd[t - 1];
    int es = (t == 0) ? 0 : ss[t - 1];
    if (t < NB) { offd[t] = ed; cd[t] = ed; offs[t] = es; cs[t] = es; }
    if (t == NB - 1) { offd[NB] = sd[t]; offs[NB] = ss[t]; }
}

// ---------------- Kernel S: block counting-sort scatter -----------
__launch_bounds__(1024)
__global__ void k_scatter(const uint32_t* __restrict__ keys, const float* __restrict__ ew,
                          int* __restrict__ cd, int* __restrict__ cs,
                          uint2* __restrict__ bdw, uint32_t* __restrict__ bs,
                          int E, int NB) {
    __shared__ int lhd[NBMAX], lhs[NBMAX];
    __shared__ int bD[NBMAX], bS[NBMAX];
    int t = threadIdx.x;
    int e0 = blockIdx.x * SCH;
    int e1 = min(e0 + SCH, E);
    if (t < NBMAX) { lhd[t] = 0; lhs[t] = 0; }
    __syncthreads();
    for (int e = e0 + t; e < e1; e += 1024) {
        uint32_t k = keys[e];
        atomicAdd(&lhd[(k >> 8) & 0xff], 1);
        atomicAdd(&lhs[k >> 24], 1);
    }
    __syncthreads();
    if (t < NB) {
        bD[t] = lhd[t] ? atomicAdd(&cd[t], lhd[t]) : 0;
        bS[t] = lhs[t] ? atomicAdd(&cs[t], lhs[t]) : 0;
        lhd[t] = 0; lhs[t] = 0;
    }
    __syncthreads();
    for (int e = e0 + t; e < e1; e += 1024) {
        uint32_t k = keys[e];
        float w = ew[e];
        int db = (k >> 8) & 0xff;
        int sb = k >> 24;
        int rd = atomicAdd(&lhd[db], 1);
        uint2 rec;
        rec.x = k;
        rec.y = __float_as_uint(w);
        bdw[bD[db] + rd] = rec;
        int rs = atomicAdd(&lhs[sb], 1);
        __half hw = __float2half(w);
        bs[bS[sb] + rs] = ((uint32_t)*(uint16_t*)&hw << 16) | ((k >> 16) & 0xffu);
    }
}

// ---------------- Kernel C: consume bins -> partials --------------
// SPLIT blocks per bin, each handles 1/SPLIT of the bin's records and
// writes a [PR][8] f32 partial with plain coalesced stores.
__launch_bounds__(1024)
__global__ void k_consume(const uint2* __restrict__ bdw, const uint32_t* __restrict__ bs,
                          const int* __restrict__ offd, const int* __restrict__ offs,
                          const float* __restrict__ x, float* __restrict__ pbuf, int N) {
    __shared__ float accx[PR][6];   // xs0..xs4, cnt
    __shared__ float accd[PR];      // deg
    int t = threadIdx.x;
    int b = blockIdx.x;
    int bin = b >> 2, sl = b & 3;

    for (int k = t; k < PR * 6; k += 1024) (&accx[0][0])[k] = 0.f;
    for (int k = t; k < PR; k += 1024) accd[k] = 0.f;
    __syncthreads();

    int r0 = offd[bin], r1 = offd[bin + 1];
    int cnt = r1 - r0, q = (cnt + SPLIT - 1) >> 2;
    int rs_ = r0 + sl * q, re_ = min(rs_ + q, r1);
    for (int r = rs_ + t; r < re_; r += 1024) {
        uint32_t k = bdw[r].x;
        uint32_t src = k >> 16;
        uint32_t dl = k & 0xffu;
        const float* xp = x + (size_t)src * 5;
        atomicAdd(&accx[dl][0], xp[0]);
        atomicAdd(&accx[dl][1], xp[1]);
        atomicAdd(&accx[dl][2], xp[2]);
        atomicAdd(&accx[dl][3], xp[3]);
        atomicAdd(&accx[dl][4], xp[4]);
        atomicAdd(&accx[dl][5], 1.0f);
    }
    int s0 = offs[bin], s1 = offs[bin + 1];
    cnt = s1 - s0; q = (cnt + SPLIT - 1) >> 2;
    rs_ = s0 + sl * q; re_ = min(rs_ + q, s1);
    for (int r = rs_ + t; r < re_; r += 1024) {
        uint32_t k = bs[r];
        uint16_t hw = (uint16_t)(k >> 16);
        atomicAdd(&accd[k & 0xffu], __half2float(*(__half*)&hw));
    }
    __syncthreads();

    float* pb = pbuf + (size_t)b * (PR * 8);
    for (int n = t; n < PR; n += 1024) {
        *(float4*)(pb + n * 8)     = make_float4(accx[n][0], accx[n][1], accx[n][2], accx[n][3]);
        *(float4*)(pb + n * 8 + 4) = make_float4(accx[n][4], accx[n][5], accd[n], 0.f);
    }
}

// ---------------- Kernel C2: finalize partials -> ninfo -----------
__launch_bounds__(256)
__global__ void k_finalize(const float* __restrict__ pbuf, float* __restrict__ ninfo, int N) {
    int n = blockIdx.x * 256 + threadIdx.x;
    if (n >= N) return;
    int bin = n >> 8, loc = n & 255;
    float a0 = 0, a1 = 0, a2 = 0, a3 = 0, a4 = 0, ct = 0, dg = 0;
    #pragma unroll
    for (int sl = 0; sl < SPLIT; sl++) {
        const float* pb = pbuf + ((size_t)(bin * SPLIT + sl)) * (PR * 8) + loc * 8;
        float4 lo = *(const float4*)pb;
        float4 hi = *(const float4*)(pb + 4);
        a0 += lo.x; a1 += lo.y; a2 += lo.z; a3 += lo.w;
        a4 += hi.x; ct += hi.y; dg += hi.z;
    }
    float dis = (dg > 0.f) ? rsqrtf(fmaxf(dg, 1e-30f)) : 0.f;
    float* o = ninfo + (size_t)n * 8;
    *(float4*)(o + 0) = make_float4(a0, a1, a2, a3);
    *(float4*)(o + 4) = make_float4(a4, ct, dg, dis);
}

// ---------------- Kernel B: fused node phase + MFMA pooled --------
// node phase: 32 threads/node (sub = t&31, cols sub+32j), weights in LDS.
// Double-buffered St/Yt: ONE barrier per tile. No min-waves bound (forcing
// 8 waves/EU caps regs at 64 and spills -- round-13 lesson).
#define STRD 40
__launch_bounds__(1024)
__global__ void k_node(const float* __restrict__ x,
                       const float* __restrict__ ninfo,
                       const float* __restrict__ W1p, const float* __restrict__ R1p,
                       const float* __restrict__ b1p,
                       const float* __restrict__ W1e, const float* __restrict__ R1e,
                       const float* __restrict__ b1e,
                       uint32_t* __restrict__ Sq, float* __restrict__ csc,
                       uint32_t* __restrict__ parts,
                       float* __restrict__ scal, int N) {
    __shared__ __half St[2][256 * STRD];  // 2 x 20 KB
    __shared__ __half Yt[2][128 * STRD];  // 2 x 10 KB
    __shared__ float Wc[10][256];         // 10 KB
    __shared__ float bc[256];
    __shared__ float We[10][128];         // 5 KB
    __shared__ float be[128];
    __shared__ float red[16];

    int t = threadIdx.x;
    int wv = t >> 6, lane = t & 63;
    int nl = t >> 5, sub = t & 31;

    for (int k = t; k < 2560; k += 1024) Wc[k >> 8][k & 255] = (k < 1280) ? W1p[k] : R1p[k - 1280];
    for (int k = t; k < 1280; k += 1024) We[k >> 7][k & 127] = (k < 640) ? W1e[k] : R1e[k - 640];
    if (t < 256) bc[t] = b1p[t];
    if (t < 128) be[t] = b1e[t];
    __syncthreads();

    f32x4 acc[8];
    #pragma unroll
    for (int ft = 0; ft < 8; ft++) acc[ft] = (f32x4){0.f, 0.f, 0.f, 0.f};
    float ssq = 0.f;
    int p = 0;

    int ntiles = (N + 31) >> 5;
    for (int tile = blockIdx.x; tile < ntiles; tile += (int)gridDim.x) {
        int i = tile * 32 + nl;
        if (i < N) {
            const float4* ni = (const float4*)(ninfo + (size_t)i * 8);
            float4 plo = ni[0];
            float4 phi = ni[1];
            float dg = phi.z;
            float dis = phi.w;
            float inv_dn = 1.0f / fmaxf(phi.y, 1.0f);
            float z[10];
            z[0] = plo.x * inv_dn; z[1] = plo.y * inv_dn; z[2] = plo.z * inv_dn;
            z[3] = plo.w * inv_dn; z[4] = phi.x * inv_dn;
            const float* xp = x + (size_t)i * 5;
            z[5] = xp[0]; z[6] = xp[1]; z[7] = xp[2]; z[8] = xp[3]; z[9] = xp[4];
            float m[8];
            #pragma unroll
            for (int j = 0; j < 8; j++) {
                int c = sub + 32 * j;
                float v = bc[c];
                #pragma unroll
                for (int d = 0; d < 10; d++) v += z[d] * Wc[d][c];
                m[j] = v;
            }
            float mx = m[0];
            #pragma unroll
            for (int j = 1; j < 8; j++) mx = fmaxf(mx, m[j]);
            #pragma unroll
            for (int o = 16; o > 0; o >>= 1) mx = fmaxf(mx, __shfl_xor(mx, o));
            float ls = 0.f;
            #pragma unroll
            for (int j = 0; j < 8; j++) { m[j] = __expf(m[j] - mx); ls += m[j]; }
            #pragma unroll
            for (int o = 16; o > 0; o >>= 1) ls += __shfl_xor(ls, o);
            float inv_l = 1.0f / ls;
            // quantize e=exp(m-mx) in [0,1] to uint4 with implicit row scale
            uint32_t qp = 0;
            #pragma unroll
            for (int j = 0; j < 8; j++) {
                int q = __float2int_rn(m[j] * 15.f);
                qp |= (uint32_t)min(q, 15) << (4 * j);
            }
            Sq[(size_t)i * 32 + sub] = qp;
            if (sub == 0) csc[i] = dis * inv_l * (1.0f / 15.0f);
            float sq = 0.f;
            #pragma unroll
            for (int j = 0; j < 8; j++) {
                float s = m[j] * inv_l;
                m[j] = s;
                sq += s * s;
                St[p][(sub + 32 * j) * STRD + nl] = __float2half(s);
            }
            if (dg > 0.f) ssq += sq;
            #pragma unroll
            for (int j = 0; j < 4; j++) {
                int f = sub + 32 * j;
                float v = be[f];
                #pragma unroll
                for (int d = 0; d < 10; d++) v += z[d] * We[d][f];
                Yt[p][f * STRD + nl] = __float2half(fmaxf(v, 0.f));
            }
        } else {
            #pragma unroll
            for (int j = 0; j < 8; j++) St[p][(sub + 32 * j) * STRD + nl] = __half(0.f);
            #pragma unroll
            for (int j = 0; j < 4; j++) Yt[p][(sub + 32 * j) * STRD + nl] = __half(0.f);
        }
        __syncthreads();
        // MFMA: wave wv owns c-tile wv (c = wv*16..+16), all 8 f-tiles, K=32.
        {
            int r = lane & 15, kc = lane >> 4;     // k = kc*8 + reg
            uint4 au = *(const uint4*)&St[p][(wv * 16 + r) * STRD + kc * 8];
            f16x8 a = __builtin_bit_cast(f16x8, au);
            #pragma unroll
            for (int ft = 0; ft < 8; ft++) {
                uint4 bu = *(const uint4*)&Yt[p][(ft * 16 + r) * STRD + kc * 8];
                f16x8 b = __builtin_bit_cast(f16x8, bu);
                acc[ft] = __builtin_amdgcn_mfma_f32_16x16x32_f16(a, b, acc[ft], 0, 0, 0);
            }
        }
        p ^= 1;
    }

    // lane-interleaved bf16-pair store: word w = wv*1024 + (ft*2+h)*64 + lane
    {
        uint32_t* pw = parts + (size_t)blockIdx.x * 16384 + wv * 1024 + lane;
        #pragma unroll
        for (int ft = 0; ft < 8; ft++) {
            __hip_bfloat162 h0, h1;
            h0.x = __float2bfloat16(acc[ft][0]);
            h0.y = __float2bfloat16(acc[ft][1]);
            h1.x = __float2bfloat16(acc[ft][2]);
            h1.y = __float2bfloat16(acc[ft][3]);
            pw[(ft * 2) * 64]     = *(uint32_t*)&h0;
            pw[(ft * 2 + 1) * 64] = *(uint32_t*)&h1;
        }
    }

    #pragma unroll
    for (int o = 32; o > 0; o >>= 1) ssq += __shfl_xor(ssq, o);
    if (lane == 0) red[wv] = ssq;
    __syncthreads();
    if (t == 0) {
        float s = 0.f;
        #pragma unroll
        for (int w2 = 0; w2 < 16; w2++) s += red[w2];
        atomicAdd(&scal[0], s);
    }
}

// ---------------- Kernel B2: reduce partials (depermute) ----------
__global__ void k_reduce(const uint32_t* __restrict__ parts,
                         float* __restrict__ pooled, int nparts) {
    int w = blockIdx.x * blockDim.x + threadIdx.x;  // 16384 total
    float s0 = 0.f, s1 = 0.f;
    #pragma unroll 4
    for (int q = 0; q < nparts; q++) {
        uint32_t v = parts[(size_t)q * 16384 + w];
        __hip_bfloat162 h = *(__hip_bfloat162*)&v;
        s0 += __bfloat162float(h.x);
        s1 += __bfloat162float(h.y);
    }
    int lane = w & 63, idx = (w >> 6) & 15, wv = w >> 10;
    int ft = idx >> 1, h = idx & 1;
    int c = wv * 16 + ((lane >> 4) & 3) * 4 + 2 * h;
    int f = ft * 16 + (lane & 15);
    pooled[c * 128 + f] = s0;
    pooled[(c + 1) * 128 + f] = s1;
}

// ---------------- Kernel R: per-edge regularizer (uint4 dot) ------
// 2 lanes/edge (64B of each row), 32 edges/wave in flight.
// XCD-chunked block swizzle for dst-row L2 locality.
__launch_bounds__(256)
__global__ void k_edge_reg(const uint2* __restrict__ bdw,
                           const uint32_t* __restrict__ Sq, const float* __restrict__ csc,
                           float* __restrict__ scal, int E) {
    __shared__ float red[4];
    int t = threadIdx.x;
    int lane = t & 63;
    int sub = lane & 1;
    int grp = lane >> 1;
    int wv = t >> 6;
    int nblocks = (int)gridDim.x;
    int bid = (int)blockIdx.x;
    int swz = (bid & 7) * (nblocks >> 3) + (bid >> 3);   // nblocks % 8 == 0
    int gw = swz * (blockDim.x >> 6) + wv;
    int nwaves = nblocks * (blockDim.x >> 6);

    float acc = 0.f;
    for (int base = gw * 32; base < E; base += nwaves * 32) {
        int e = base + grp;
        int idot = 0;
        float sc = 0.f;
        if (e < E) {
            uint2 rec = bdw[e];
            uint32_t k = rec.x;
            int s = (int)(k >> 16);
            int d = (int)(k & 0xffffu);
            const uint4* pa = (const uint4*)(Sq + (size_t)s * 32) + sub * 4;
            const uint4* pb = (const uint4*)(Sq + (size_t)d * 32) + sub * 4;
            #pragma unroll
            for (int q = 0; q < 4; q++) {
                uint4 A = pa[q];
                uint4 B = pb[q];
                idot = udot8(A.x, B.x, idot);
                idot = udot8(A.y, B.y, idot);
                idot = udot8(A.z, B.z, idot);
                idot = udot8(A.w, B.w, idot);
            }
            sc = __uint_as_float(rec.y) * csc[s] * csc[d];
        }
        idot += __shfl_xor(idot, 1);
        if (sub == 0) acc += sc * (float)idot;
    }

    #pragma unroll
    for (int o = 32; o > 0; o >>= 1) acc += __shfl_xor(acc, o);
    if (lane == 0) red[wv] = acc;
    __syncthreads();
    if (t == 0) atomicAdd(&scal[1], red[0] + red[1] + red[2] + red[3]);
}

// ---------------- Kernel D1: y2 column sums -----------------------
__launch_bounds__(256)
__global__ void k_pool2(const float* __restrict__ pooled,
                        const float* __restrict__ W2e, const float* __restrict__ R2e,
                        const float* __restrict__ b2e, float* __restrict__ g) {
    __shared__ float mh[128];
    __shared__ float prow[128];
    int t = threadIdx.x;
    int c = blockIdx.x;
    if (t < 128) {
        float s = 0.f;
        for (int cc = 0; cc < 256; cc++) s += pooled[cc * 128 + t];
        mh[t] = s * (1.0f / 256.0f);
        prow[t] = pooled[c * 128 + t];
    }
    __syncthreads();
    float v = b2e[t];
    for (int k = 0; k < 128; k++)
        v += mh[k] * W2e[k * 256 + t] + prow[k] * R2e[k * 256 + t];
    v = fmaxf(v, 0.f);
    atomicAdd(&g[t], v);
}

// ---------------- Kernel D2: final MLP + output -------------------
__launch_bounds__(256)
__global__ void k_final(const float* __restrict__ g,
                        const float* __restrict__ Wl1, const float* __restrict__ bl1,
                        const float* __restrict__ Wl2, const float* __restrict__ bl2,
                        const float* __restrict__ scal, float* __restrict__ out, int N) {
    __shared__ float gs[256];
    __shared__ float h1[256];
    __shared__ float lg[10];
    int t = threadIdx.x;
    gs[t] = g[t];
    __syncthreads();
    float v = bl1[t];
    for (int k = 0; k < 256; k++) v += gs[k] * Wl1[k * 256 + t];
    h1[t] = fmaxf(v, 0.f);
    __syncthreads();
    if (t < 10) {
        float s = bl2[t];
        for (int k = 0; k < 256; k++) s += h1[k] * Wl2[k * 10 + t];
        lg[t] = s;
    }
    __syncthreads();
    if (t == 0) {
        float mx = lg[0];
        for (int j = 1; j < 10; j++) mx = fmaxf(mx, lg[j]);
        float ls = 0.f;
        for (int j = 0; j < 10; j++) ls += __expf(lg[j] - mx);
        float lse = mx + logf(ls);
        for (int j = 0; j < 10; j++) out[j] = lg[j] - lse;
        out[10] = (scal[0] - scal[1]) / (float)N;
    }
}

extern "C" void kernel_launch(void* const* d_in, const int* in_sizes, int n_in,
                              void* d_out, int out_size, void* d_ws, size_t ws_size,
                              hipStream_t stream) {
    const float* x   = (const float*)d_in[0];
    const int*   ei  = (const int*)d_in[1];
    const float* ew  = (const float*)d_in[2];
    const float* W1p = (const float*)d_in[3];
    const float* R1p = (const float*)d_in[4];
    const float* b1p = (const float*)d_in[5];
    const float* W1e = (const float*)d_in[6];
    const float* R1e = (const float*)d_in[7];
    const float* b1e = (const float*)d_in[8];
    // d_in[9..11] = W2p,R2p,b2p : dead (softmax over size-1 axis == 1)
    const float* W2e = (const float*)d_in[12];
    const float* R2e = (const float*)d_in[13];
    const float* b2e = (const float*)d_in[14];
    const float* Wl1 = (const float*)d_in[15];
    const float* bl1 = (const float*)d_in[16];
    const float* Wl2 = (const float*)d_in[17];
    const float* bl2 = (const float*)d_in[18];
    float* out = (float*)d_out;

    int N = in_sizes[0] / 5;
    int E = in_sizes[1] / 2;
    int NB = (N + PR - 1) / PR;

    uint32_t* ws = (uint32_t*)d_ws;
    size_t off = 0;
    float* g    = (float*)(ws + off); off += 256;
    float* scal = (float*)(ws + off); off += 2;
    int* hd = (int*)(ws + off); off += NBMAX;
    int* hs = (int*)(ws + off); off += NBMAX;
    size_t zero_words = off;                       // accumulators to clear
    int* offd = (int*)(ws + off); off += NBMAX + 1;
    int* offs = (int*)(ws + off); off += NBMAX + 1;
    int* cd   = (int*)(ws + off); off += NBMAX;
    int* cs   = (int*)(ws + off); off += NBMAX;
    off = (off + 3) & ~(size_t)3;                  // 16B align
    float* ninfo = (float*)(ws + off); off += (size_t)N * 8;
    float* csc   = (float*)(ws + off); off += (size_t)N;
    uint32_t* keys = ws + off; off += (size_t)E;
    off = (off + 1) & ~(size_t)1;                  // 8B align
    uint2* bdw = (uint2*)(ws + off); off += (size_t)E * 2;
    uint32_t* bs = ws + off; off += (size_t)E;
    off = (off + 3) & ~(size_t)3;
    uint32_t* Sq = ws + off; off += (size_t)N * 32;
    float* pooled = (float*)(ws + off); off += 32768;
    size_t avail = (ws_size / 4 > off) ? (ws_size / 4 - off) : 0;
    int nparts = (int)(avail / 16384);
    if (nparts > 256) nparts = 256;
    if (nparts < 1) nparts = 1;
    uint32_t* parts = ws + off;
    float* pbuf = (float*)parts;   // aliases parts; consume+finalize precede k_node

    hipMemsetAsync(d_ws, 0, zero_words * 4, stream);

    k_hist<<<104, 1024, 0, stream>>>(ei, keys, hd, hs, E);
    k_prefix<<<1, NBMAX, 0, stream>>>(hd, hs, offd, offs, cd, cs, NB);
    k_scatter<<<(E + SCH - 1) / SCH, 1024, 0, stream>>>(keys, ew, cd, cs, bdw, bs, E, NB);
    k_consume<<<NB * SPLIT, 1024, 0, stream>>>(bdw, bs, offd, offs, x, pbuf, N);
    k_finalize<<<(N + 255) / 256, 256, 0, stream>>>(pbuf, ninfo, N);
    k_node<<<nparts, 1024, 0, stream>>>(x, ninfo, W1p, R1p, b1p,
                                        W1e, R1e, b1e, Sq, csc, parts, scal, N);
    k_reduce<<<64, 256, 0, stream>>>(parts, pooled, nparts);
    k_edge_reg<<<2048, 256, 0, stream>>>(bdw, Sq, csc, scal, E);
    k_pool2<<<256, 256, 0, stream>>>(pooled, W2e, R2e, b2e, g);
    k_final<<<1, 256, 0, stream>>>(g, Wl1, bl1, Wl2, bl2, scal, out, N);
}

// Round 16
// 211.712 us; speedup vs baseline: 1.0404x; 1.0404x over previous
//
#include <hip/hip_runtime.h>
#include <hip/hip_bf16.h>
#include <hip/hip_fp16.h>

// ---------------- workspace layout (u32 words) ----------------
// g     [256]   f32 (atomic accum, memset 0)
// scal  [2]     f32 (ssq, sasn) (atomic accum, memset 0)
// hd    [256]   int dst-bucket histogram (memset 0)
// hs    [256]   int src-bucket histogram (memset 0)
// offd  [257], offs [257], cd [256], cs [256]  (written by k_prefix)
// ninfo [N*8]   f32 {xs0..xs4, cnt, deg, dis}
// csc   [N]     f32 = dis * inv_l / 15
// keys  [E]     u32 (src<<16 | dst)  -- requires N <= 65536 (N=50000)
// bdw   [E]     uint2 {key, f32 w} dst-binned records
// bs    [E]     u32 src-binned {h16(ew)<<16 | src&0xff}
// Sq    [N*32]  u32 = 256 uint4-vals/node (q=rint(exp(m-mx)*15), permuted)
// pooled[32768] f32
// parts [nparts*16384 u32] (lane-interleaved bf16 pairs)

#define PR 256
#define NBMAX 256
#define SCH 4096

typedef _Float16 f16x8 __attribute__((ext_vector_type(8)));
typedef float f32x4 __attribute__((ext_vector_type(4)));

__device__ inline int udot8(uint32_t a, uint32_t b, int c) {
#if __has_builtin(__builtin_amdgcn_udot8)
    return __builtin_amdgcn_udot8(a, b, c, false);
#else
    #pragma unroll
    for (int i = 0; i < 8; i++)
        c += (int)((a >> (4 * i)) & 15) * (int)((b >> (4 * i)) & 15);
    return c;
#endif
}

// ---------------- Kernel H: pack keys + global bucket histogram ---
__launch_bounds__(1024)
__global__ void k_hist(const int* __restrict__ ei, uint32_t* __restrict__ keys,
                       int* __restrict__ hd, int* __restrict__ hs, int E) {
    __shared__ int lhd[NBMAX], lhs[NBMAX];
    int t = threadIdx.x;
    if (t < NBMAX) { lhd[t] = 0; lhs[t] = 0; }
    __syncthreads();
    int idx = blockIdx.x * blockDim.x + t;
    int stride = gridDim.x * blockDim.x;
    for (int e = idx; e < E; e += stride) {
        uint32_t s = (uint32_t)ei[e];
        uint32_t d = (uint32_t)ei[E + e];
        keys[e] = (s << 16) | d;
        atomicAdd(&lhd[d >> 8], 1);
        atomicAdd(&lhs[s >> 8], 1);
    }
    __syncthreads();
    if (t < NBMAX) {
        if (lhd[t]) atomicAdd(&hd[t], lhd[t]);
        if (lhs[t]) atomicAdd(&hs[t], lhs[t]);
    }
}

// ---------------- Kernel X: parallel exclusive prefix -------------
__launch_bounds__(NBMAX)
__global__ void k_prefix(const int* __restrict__ hd, const int* __restrict__ hs,
                         int* __restrict__ offd, int* __restrict__ offs,
                         int* __restrict__ cd, int* __restrict__ cs, int NB) {
    __shared__ int sd[NBMAX], ss[NBMAX];
    int t = threadIdx.x;
    sd[t] = (t < NB) ? hd[t] : 0;
    ss[t] = (t < NB) ? hs[t] : 0;
    __syncthreads();
    #pragma unroll
    for (int o = 1; o < NBMAX; o <<= 1) {
        int vd = (t >= o) ? sd[t - o] : 0;
        int vs = (t >= o) ? ss[t - o] : 0;
        __syncthreads();
        sd[t] += vd; ss[t] += vs;
        __syncthreads();
    }
    int ed = (t == 0) ? 0 : sd[t - 1];
    int es = (t == 0) ? 0 : ss[t - 1];
    if (t < NB) { offd[t] = ed; cd[t] = ed; offs[t] = es; cs[t] = es; }
    if (t == NB - 1) { offd[NB] = sd[t]; offs[NB] = ss[t]; }
}

// ---------------- Kernel S: block counting-sort scatter -----------
__launch_bounds__(1024)
__global__ void k_scatter(const uint32_t* __restrict__ keys, const float* __restrict__ ew,
                          int* __restrict__ cd, int* __restrict__ cs,
                          uint2* __restrict__ bdw, uint32_t* __restrict__ bs,
                          int E, int NB) {
    __shared__ int lhd[NBMAX], lhs[NBMAX];
    __shared__ int bD[NBMAX], bS[NBMAX];
    int t = threadIdx.x;
    int e0 = blockIdx.x * SCH;
    int e1 = min(e0 + SCH, E);
    if (t < NBMAX) { lhd[t] = 0; lhs[t] = 0; }
    __syncthreads();
    for (int e = e0 + t; e < e1; e += 1024) {
        uint32_t k = keys[e];
        atomicAdd(&lhd[(k >> 8) & 0xff], 1);
        atomicAdd(&lhs[k >> 24], 1);
    }
    __syncthreads();
    if (t < NB) {
        bD[t] = lhd[t] ? atomicAdd(&cd[t], lhd[t]) : 0;
        bS[t] = lhs[t] ? atomicAdd(&cs[t], lhs[t]) : 0;
        lhd[t] = 0; lhs[t] = 0;
    }
    __syncthreads();
    for (int e = e0 + t; e < e1; e += 1024) {
        uint32_t k = keys[e];
        float w = ew[e];
        int db = (k >> 8) & 0xff;
        int sb = k >> 24;
        int rd = atomicAdd(&lhd[db], 1);
        uint2 rec;
        rec.x = k;
        rec.y = __float_as_uint(w);
        bdw[bD[db] + rd] = rec;
        int rs = atomicAdd(&lhs[sb], 1);
        __half hw = __float2half(w);
        bs[bS[sb] + rs] = ((uint32_t)*(uint16_t*)&hw << 16) | ((k >> 16) & 0xffu);
    }
}

// ---------------- Kernel C: consume bins -> ninfo -----------------
__launch_bounds__(1024)
__global__ void k_consume(const uint2* __restrict__ bdw, const uint32_t* __restrict__ bs,
                          const int* __restrict__ offd, const int* __restrict__ offs,
                          const float* __restrict__ x, float* __restrict__ ninfo, int N) {
    __shared__ float accx[PR][6];   // xs0..xs4, cnt
    __shared__ float accd[PR];      // deg
    int t = threadIdx.x;
    int b = blockIdx.x;
    int base = b * PR;
    uint32_t pr = (uint32_t)min(PR, N - base);

    for (int k = t; k < PR * 6; k += 1024) (&accx[0][0])[k] = 0.f;
    for (int k = t; k < PR; k += 1024) accd[k] = 0.f;
    __syncthreads();

    int r0 = offd[b], r1 = offd[b + 1];
    for (int r = r0 + t; r < r1; r += 1024) {
        uint32_t k = bdw[r].x;
        uint32_t src = k >> 16;
        uint32_t dl = k & 0xffu;
        const float* xp = x + (size_t)src * 5;
        atomicAdd(&accx[dl][0], xp[0]);
        atomicAdd(&accx[dl][1], xp[1]);
        atomicAdd(&accx[dl][2], xp[2]);
        atomicAdd(&accx[dl][3], xp[3]);
        atomicAdd(&accx[dl][4], xp[4]);
        atomicAdd(&accx[dl][5], 1.0f);
    }
    int s0 = offs[b], s1 = offs[b + 1];
    for (int r = s0 + t; r < s1; r += 1024) {
        uint32_t k = bs[r];
        uint16_t hw = (uint16_t)(k >> 16);
        atomicAdd(&accd[k & 0xffu], __half2float(*(__half*)&hw));
    }
    __syncthreads();

    for (uint32_t n = t; n < pr; n += 1024) {
        float dg = accd[n];
        float dis = (dg > 0.f) ? rsqrtf(fmaxf(dg, 1e-30f)) : 0.f;
        float* o = ninfo + (size_t)(base + n) * 8;
        *(float4*)(o + 0) = make_float4(accx[n][0], accx[n][1], accx[n][2], accx[n][3]);
        *(float4*)(o + 4) = make_float4(accx[n][4], accx[n][5], dg, dis);
    }
}

// ---------------- Kernel B: fused node phase + MFMA pooled --------
// node phase: 32 threads/node (sub = t&31, cols sub+32j), weights in LDS.
// Double-buffered St/Yt: ONE barrier per tile. No min-waves bound (forcing
// 8 waves/EU caps regs at 64 and spills -- round-13 lesson).
#define STRD 40
__launch_bounds__(1024)
__global__ void k_node(const float* __restrict__ x,
                       const float* __restrict__ ninfo,
                       const float* __restrict__ W1p, const float* __restrict__ R1p,
                       const float* __restrict__ b1p,
                       const float* __restrict__ W1e, const float* __restrict__ R1e,
                       const float* __restrict__ b1e,
                       uint32_t* __restrict__ Sq, float* __restrict__ csc,
                       uint32_t* __restrict__ parts,
                       float* __restrict__ scal, int N) {
    __shared__ __half St[2][256 * STRD];  // 2 x 20 KB
    __shared__ __half Yt[2][128 * STRD];  // 2 x 10 KB
    __shared__ float Wc[10][256];         // 10 KB
    __shared__ float bc[256];
    __shared__ float We[10][128];         // 5 KB
    __shared__ float be[128];
    __shared__ float red[16];

    int t = threadIdx.x;
    int wv = t >> 6, lane = t & 63;
    int nl = t >> 5, sub = t & 31;

    for (int k = t; k < 2560; k += 1024) Wc[k >> 8][k & 255] = (k < 1280) ? W1p[k] : R1p[k - 1280];
    for (int k = t; k < 1280; k += 1024) We[k >> 7][k & 127] = (k < 640) ? W1e[k] : R1e[k - 640];
    if (t < 256) bc[t] = b1p[t];
    if (t < 128) be[t] = b1e[t];
    __syncthreads();

    f32x4 acc[8];
    #pragma unroll
    for (int ft = 0; ft < 8; ft++) acc[ft] = (f32x4){0.f, 0.f, 0.f, 0.f};
    float ssq = 0.f;
    int p = 0;

    int ntiles = (N + 31) >> 5;
    for (int tile = blockIdx.x; tile < ntiles; tile += (int)gridDim.x) {
        int i = tile * 32 + nl;
        if (i < N) {
            const float4* ni = (const float4*)(ninfo + (size_t)i * 8);
            float4 plo = ni[0];
            float4 phi = ni[1];
            float dg = phi.z;
            float dis = phi.w;
            float inv_dn = 1.0f / fmaxf(phi.y, 1.0f);
            float z[10];
            z[0] = plo.x * inv_dn; z[1] = plo.y * inv_dn; z[2] = plo.z * inv_dn;
            z[3] = plo.w * inv_dn; z[4] = phi.x * inv_dn;
            const float* xp = x + (size_t)i * 5;
            z[5] = xp[0]; z[6] = xp[1]; z[7] = xp[2]; z[8] = xp[3]; z[9] = xp[4];
            float m[8];
            #pragma unroll
            for (int j = 0; j < 8; j++) {
                int c = sub + 32 * j;
                float v = bc[c];
                #pragma unroll
                for (int d = 0; d < 10; d++) v += z[d] * Wc[d][c];
                m[j] = v;
            }
            float mx = m[0];
            #pragma unroll
            for (int j = 1; j < 8; j++) mx = fmaxf(mx, m[j]);
            #pragma unroll
            for (int o = 16; o > 0; o >>= 1) mx = fmaxf(mx, __shfl_xor(mx, o));
            float ls = 0.f;
            #pragma unroll
            for (int j = 0; j < 8; j++) { m[j] = __expf(m[j] - mx); ls += m[j]; }
            #pragma unroll
            for (int o = 16; o > 0; o >>= 1) ls += __shfl_xor(ls, o);
            float inv_l = 1.0f / ls;
            // quantize e=exp(m-mx) in [0,1] to uint4 with implicit row scale
            uint32_t qp = 0;
            #pragma unroll
            for (int j = 0; j < 8; j++) {
                int q = __float2int_rn(m[j] * 15.f);
                qp |= (uint32_t)min(q, 15) << (4 * j);
            }
            Sq[(size_t)i * 32 + sub] = qp;
            if (sub == 0) csc[i] = dis * inv_l * (1.0f / 15.0f);
            float sq = 0.f;
            #pragma unroll
            for (int j = 0; j < 8; j++) {
                float s = m[j] * inv_l;
                m[j] = s;
                sq += s * s;
                St[p][(sub + 32 * j) * STRD + nl] = __float2half(s);
            }
            if (dg > 0.f) ssq += sq;
            #pragma unroll
            for (int j = 0; j < 4; j++) {
                int f = sub + 32 * j;
                float v = be[f];
                #pragma unroll
                for (int d = 0; d < 10; d++) v += z[d] * We[d][f];
                Yt[p][f * STRD + nl] = __float2half(fmaxf(v, 0.f));
            }
        } else {
            #pragma unroll
            for (int j = 0; j < 8; j++) St[p][(sub + 32 * j) * STRD + nl] = __half(0.f);
            #pragma unroll
            for (int j = 0; j < 4; j++) Yt[p][(sub + 32 * j) * STRD + nl] = __half(0.f);
        }
        __syncthreads();
        // MFMA: wave wv owns c-tile wv (c = wv*16..+16), all 8 f-tiles, K=32.
        {
            int r = lane & 15, kc = lane >> 4;     // k = kc*8 + reg
            uint4 au = *(const uint4*)&St[p][(wv * 16 + r) * STRD + kc * 8];
            f16x8 a = __builtin_bit_cast(f16x8, au);
            #pragma unroll
            for (int ft = 0; ft < 8; ft++) {
                uint4 bu = *(const uint4*)&Yt[p][(ft * 16 + r) * STRD + kc * 8];
                f16x8 b = __builtin_bit_cast(f16x8, bu);
                acc[ft] = __builtin_amdgcn_mfma_f32_16x16x32_f16(a, b, acc[ft], 0, 0, 0);
            }
        }
        p ^= 1;
    }

    // lane-interleaved bf16-pair store: word w = wv*1024 + (ft*2+h)*64 + lane
    {
        uint32_t* pw = parts + (size_t)blockIdx.x * 16384 + wv * 1024 + lane;
        #pragma unroll
        for (int ft = 0; ft < 8; ft++) {
            __hip_bfloat162 h0, h1;
            h0.x = __float2bfloat16(acc[ft][0]);
            h0.y = __float2bfloat16(acc[ft][1]);
            h1.x = __float2bfloat16(acc[ft][2]);
            h1.y = __float2bfloat16(acc[ft][3]);
            pw[(ft * 2) * 64]     = *(uint32_t*)&h0;
            pw[(ft * 2 + 1) * 64] = *(uint32_t*)&h1;
        }
    }

    #pragma unroll
    for (int o = 32; o > 0; o >>= 1) ssq += __shfl_xor(ssq, o);
    if (lane == 0) red[wv] = ssq;
    __syncthreads();
    if (t == 0) {
        float s = 0.f;
        #pragma unroll
        for (int w2 = 0; w2 < 16; w2++) s += red[w2];
        atomicAdd(&scal[0], s);
    }
}

// ---------------- Kernel B2: reduce partials (depermute) ----------
__global__ void k_reduce(const uint32_t* __restrict__ parts,
                         float* __restrict__ pooled, int nparts) {
    int w = blockIdx.x * blockDim.x + threadIdx.x;  // 16384 total
    float s0 = 0.f, s1 = 0.f;
    #pragma unroll 4
    for (int q = 0; q < nparts; q++) {
        uint32_t v = parts[(size_t)q * 16384 + w];
        __hip_bfloat162 h = *(__hip_bfloat162*)&v;
        s0 += __bfloat162float(h.x);
        s1 += __bfloat162float(h.y);
    }
    int lane = w & 63, idx = (w >> 6) & 15, wv = w >> 10;
    int ft = idx >> 1, h = idx & 1;
    int c = wv * 16 + ((lane >> 4) & 3) * 4 + 2 * h;
    int f = ft * 16 + (lane & 15);
    pooled[c * 128 + f] = s0;
    pooled[(c + 1) * 128 + f] = s1;
}

// ---------------- Kernel R: per-edge regularizer (uint4 dot) ------
// 2 lanes/edge (64B of each row), 32 edges/wave in flight.
// XCD-chunked block swizzle for dst-row L2 locality.
__launch_bounds__(256)
__global__ void k_edge_reg(const uint2* __restrict__ bdw,
                           const uint32_t* __restrict__ Sq, const float* __restrict__ csc,
                           float* __restrict__ scal, int E) {
    __shared__ float red[4];
    int t = threadIdx.x;
    int lane = t & 63;
    int sub = lane & 1;
    int grp = lane >> 1;
    int wv = t >> 6;
    int nblocks = (int)gridDim.x;
    int bid = (int)blockIdx.x;
    int swz = (bid & 7) * (nblocks >> 3) + (bid >> 3);   // nblocks % 8 == 0
    int gw = swz * (blockDim.x >> 6) + wv;
    int nwaves = nblocks * (blockDim.x >> 6);

    float acc = 0.f;
    for (int base = gw * 32; base < E; base += nwaves * 32) {
        int e = base + grp;
        int idot = 0;
        float sc = 0.f;
        if (e < E) {
            uint2 rec = bdw[e];
            uint32_t k = rec.x;
            int s = (int)(k >> 16);
            int d = (int)(k & 0xffffu);
            const uint4* pa = (const uint4*)(Sq + (size_t)s * 32) + sub * 4;
            const uint4* pb = (const uint4*)(Sq + (size_t)d * 32) + sub * 4;
            #pragma unroll
            for (int q = 0; q < 4; q++) {
                uint4 A = pa[q];
                uint4 B = pb[q];
                idot = udot8(A.x, B.x, idot);
                idot = udot8(A.y, B.y, idot);
                idot = udot8(A.z, B.z, idot);
                idot = udot8(A.w, B.w, idot);
            }
            sc = __uint_as_float(rec.y) * csc[s] * csc[d];
        }
        idot += __shfl_xor(idot, 1);
        if (sub == 0) acc += sc * (float)idot;
    }

    #pragma unroll
    for (int o = 32; o > 0; o >>= 1) acc += __shfl_xor(acc, o);
    if (lane == 0) red[wv] = acc;
    __syncthreads();
    if (t == 0) atomicAdd(&scal[1], red[0] + red[1] + red[2] + red[3]);
}

// ---------------- Kernel D1: y2 column sums -----------------------
__launch_bounds__(256)
__global__ void k_pool2(const float* __restrict__ pooled,
                        const float* __restrict__ W2e, const float* __restrict__ R2e,
                        const float* __restrict__ b2e, float* __restrict__ g) {
    __shared__ float mh[128];
    __shared__ float prow[128];
    int t = threadIdx.x;
    int c = blockIdx.x;
    if (t < 128) {
        float s = 0.f;
        for (int cc = 0; cc < 256; cc++) s += pooled[cc * 128 + t];
        mh[t] = s * (1.0f / 256.0f);
        prow[t] = pooled[c * 128 + t];
    }
    __syncthreads();
    float v = b2e[t];
    for (int k = 0; k < 128; k++)
        v += mh[k] * W2e[k * 256 + t] + prow[k] * R2e[k * 256 + t];
    v = fmaxf(v, 0.f);
    atomicAdd(&g[t], v);
}

// ---------------- Kernel D2: final MLP + output -------------------
__launch_bounds__(256)
__global__ void k_final(const float* __restrict__ g,
                        const float* __restrict__ Wl1, const float* __restrict__ bl1,
                        const float* __restrict__ Wl2, const float* __restrict__ bl2,
                        const float* __restrict__ scal, float* __restrict__ out, int N) {
    __shared__ float gs[256];
    __shared__ float h1[256];
    __shared__ float lg[10];
    int t = threadIdx.x;
    gs[t] = g[t];
    __syncthreads();
    float v = bl1[t];
    for (int k = 0; k < 256; k++) v += gs[k] * Wl1[k * 256 + t];
    h1[t] = fmaxf(v, 0.f);
    __syncthreads();
    if (t < 10) {
        float s = bl2[t];
        for (int k = 0; k < 256; k++) s += h1[k] * Wl2[k * 10 + t];
        lg[t] = s;
    }
    __syncthreads();
    if (t == 0) {
        float mx = lg[0];
        for (int j = 1; j < 10; j++) mx = fmaxf(mx, lg[j]);
        float ls = 0.f;
        for (int j = 0; j < 10; j++) ls += __expf(lg[j] - mx);
        float lse = mx + logf(ls);
        for (int j = 0; j < 10; j++) out[j] = lg[j] - lse;
        out[10] = (scal[0] - scal[1]) / (float)N;
    }
}

extern "C" void kernel_launch(void* const* d_in, const int* in_sizes, int n_in,
                              void* d_out, int out_size, void* d_ws, size_t ws_size,
                              hipStream_t stream) {
    const float* x   = (const float*)d_in[0];
    const int*   ei  = (const int*)d_in[1];
    const float* ew  = (const float*)d_in[2];
    const float* W1p = (const float*)d_in[3];
    const float* R1p = (const float*)d_in[4];
    const float* b1p = (const float*)d_in[5];
    const float* W1e = (const float*)d_in[6];
    const float* R1e = (const float*)d_in[7];
    const float* b1e = (const float*)d_in[8];
    // d_in[9..11] = W2p,R2p,b2p : dead (softmax over size-1 axis == 1)
    const float* W2e = (const float*)d_in[12];
    const float* R2e = (const float*)d_in[13];
    const float* b2e = (const float*)d_in[14];
    const float* Wl1 = (const float*)d_in[15];
    const float* bl1 = (const float*)d_in[16];
    const float* Wl2 = (const float*)d_in[17];
    const float* bl2 = (const float*)d_in[18];
    float* out = (float*)d_out;

    int N = in_sizes[0] / 5;
    int E = in_sizes[1] / 2;
    int NB = (N + PR - 1) / PR;

    uint32_t* ws = (uint32_t*)d_ws;
    size_t off = 0;
    float* g    = (float*)(ws + off); off += 256;
    float* scal = (float*)(ws + off); off += 2;
    int* hd = (int*)(ws + off); off += NBMAX;
    int* hs = (int*)(ws + off); off += NBMAX;
    size_t zero_words = off;                       // accumulators to clear
    int* offd = (int*)(ws + off); off += NBMAX + 1;
    int* offs = (int*)(ws + off); off += NBMAX + 1;
    int* cd   = (int*)(ws + off); off += NBMAX;
    int* cs   = (int*)(ws + off); off += NBMAX;
    off = (off + 3) & ~(size_t)3;                  // 16B align
    float* ninfo = (float*)(ws + off); off += (size_t)N * 8;
    float* csc   = (float*)(ws + off); off += (size_t)N;
    uint32_t* keys = ws + off; off += (size_t)E;
    off = (off + 1) & ~(size_t)1;                  // 8B align
    uint2* bdw = (uint2*)(ws + off); off += (size_t)E * 2;
    uint32_t* bs = ws + off; off += (size_t)E;
    off = (off + 3) & ~(size_t)3;
    uint32_t* Sq = ws + off; off += (size_t)N * 32;
    float* pooled = (float*)(ws + off); off += 32768;
    size_t avail = (ws_size / 4 > off) ? (ws_size / 4 - off) : 0;
    int nparts = (int)(avail / 16384);
    if (nparts > 256) nparts = 256;
    if (nparts < 1) nparts = 1;
    uint32_t* parts = ws + off;

    hipMemsetAsync(d_ws, 0, zero_words * 4, stream);

    k_hist<<<104, 1024, 0, stream>>>(ei, keys, hd, hs, E);
    k_prefix<<<1, NBMAX, 0, stream>>>(hd, hs, offd, offs, cd, cs, NB);
    k_scatter<<<(E + SCH - 1) / SCH, 1024, 0, stream>>>(keys, ew, cd, cs, bdw, bs, E, NB);
    k_consume<<<NB, 1024, 0, stream>>>(bdw, bs, offd, offs, x, ninfo, N);
    k_node<<<nparts, 1024, 0, stream>>>(x, ninfo, W1p, R1p, b1p,
                                        W1e, R1e, b1e, Sq, csc, parts, scal, N);
    k_reduce<<<64, 256, 0, stream>>>(parts, pooled, nparts);
    k_edge_reg<<<2048, 256, 0, stream>>>(bdw, Sq, csc, scal, E);
    k_pool2<<<256, 256, 0, stream>>>(pooled, W2e, R2e, b2e, g);
    k_final<<<1, 256, 0, stream>>>(g, Wl1, bl1, Wl2, bl2, scal, out, N);
}

// Round 17
// 209.889 us; speedup vs baseline: 1.0495x; 1.0087x over previous
//
#include <hip/hip_runtime.h>
#include <hip/hip_bf16.h>
#include <hip/hip_fp16.h>

// ---------------- workspace layout (u32 words) ----------------
// g     [256]   f32 (atomic accum, zeroed by k_prefix)
// scal  [2]     f32 (ssq, sasn) (atomic accum, zeroed by k_prefix)
// hpriv [NHIST*512] int private per-block histograms (plain stores)
// offd  [257], offs [257], cd [256], cs [256]  (written by k_prefix)
// ninfo [N*8]   f32 {xs0..xs4, cnt, deg, dis}
// csc   [N]     f32 = dis * inv_l / 15
// keys  [E]     u32 (src<<16 | dst)  -- requires N <= 65536 (N=50000)
// bdw   [E]     uint2 {key, f32 w} dst-binned records
// bs    [E]     u32 src-binned {h16(ew)<<16 | src&0xff}
// Sq    [N*32]  u32 = 256 uint4-vals/node (q=rint(exp(m-mx)*15), permuted)
// pooled[32768] f32
// parts [nparts*16384 u32] (lane-interleaved bf16 pairs)

#define PR 256
#define NBMAX 256
#define SCH 4096
#define NHIST 104

typedef _Float16 f16x8 __attribute__((ext_vector_type(8)));
typedef float f32x4 __attribute__((ext_vector_type(4)));

__device__ inline int udot8(uint32_t a, uint32_t b, int c) {
#if __has_builtin(__builtin_amdgcn_udot8)
    return __builtin_amdgcn_udot8(a, b, c, false);
#else
    #pragma unroll
    for (int i = 0; i < 8; i++)
        c += (int)((a >> (4 * i)) & 15) * (int)((b >> (4 * i)) & 15);
    return c;
#endif
}

// ---------------- Kernel H: pack keys + private histograms --------
__launch_bounds__(1024)
__global__ void k_hist(const int* __restrict__ ei, uint32_t* __restrict__ keys,
                       int* __restrict__ hpriv, int E) {
    __shared__ int lhd[NBMAX], lhs[NBMAX];
    int t = threadIdx.x;
    if (t < NBMAX) { lhd[t] = 0; lhs[t] = 0; }
    __syncthreads();
    int idx = blockIdx.x * blockDim.x + t;
    int stride = gridDim.x * blockDim.x;
    for (int e = idx; e < E; e += stride) {
        uint32_t s = (uint32_t)ei[e];
        uint32_t d = (uint32_t)ei[E + e];
        keys[e] = (s << 16) | d;
        atomicAdd(&lhd[d >> 8], 1);
        atomicAdd(&lhs[s >> 8], 1);
    }
    __syncthreads();
    if (t < NBMAX) {
        hpriv[(size_t)(blockIdx.x * 2) * NBMAX + t]     = lhd[t];
        hpriv[(size_t)(blockIdx.x * 2 + 1) * NBMAX + t] = lhs[t];
    }
}

// ---------------- Kernel X: sum private hists + prefix + zero -----
__launch_bounds__(NBMAX)
__global__ void k_prefix(const int* __restrict__ hpriv,
                         int* __restrict__ offd, int* __restrict__ offs,
                         int* __restrict__ cd, int* __restrict__ cs,
                         float* __restrict__ g, float* __restrict__ scal, int NB) {
    __shared__ int sd[NBMAX], ss[NBMAX];
    int t = threadIdx.x;
    int hd_t = 0, hs_t = 0;
    for (int b = 0; b < NHIST; b++) {
        hd_t += hpriv[(size_t)(b * 2) * NBMAX + t];
        hs_t += hpriv[(size_t)(b * 2 + 1) * NBMAX + t];
    }
    sd[t] = (t < NB) ? hd_t : 0;
    ss[t] = (t < NB) ? hs_t : 0;
    // zero accumulators for this launch
    g[t] = 0.f;
    if (t < 2) scal[t] = 0.f;
    __syncthreads();
    #pragma unroll
    for (int o = 1; o < NBMAX; o <<= 1) {
        int vd = (t >= o) ? sd[t - o] : 0;
        int vs = (t >= o) ? ss[t - o] : 0;
        __syncthreads();
        sd[t] += vd; ss[t] += vs;
        __syncthreads();
    }
    int ed = (t == 0) ? 0 : sd[t - 1];
    int es = (t == 0) ? 0 : ss[t - 1];
    if (t < NB) { offd[t] = ed; cd[t] = ed; offs[t] = es; cs[t] = es; }
    if (t == NB - 1) { offd[NB] = sd[t]; offs[NB] = ss[t]; }
}

// ---------------- Kernel S: block counting-sort scatter -----------
__launch_bounds__(1024)
__global__ void k_scatter(const uint32_t* __restrict__ keys, const float* __restrict__ ew,
                          int* __restrict__ cd, int* __restrict__ cs,
                          uint2* __restrict__ bdw, uint32_t* __restrict__ bs,
                          int E, int NB) {
    __shared__ int lhd[NBMAX], lhs[NBMAX];
    __shared__ int bD[NBMAX], bS[NBMAX];
    int t = threadIdx.x;
    int e0 = blockIdx.x * SCH;
    int e1 = min(e0 + SCH, E);
    if (t < NBMAX) { lhd[t] = 0; lhs[t] = 0; }
    __syncthreads();
    for (int e = e0 + t; e < e1; e += 1024) {
        uint32_t k = keys[e];
        atomicAdd(&lhd[(k >> 8) & 0xff], 1);
        atomicAdd(&lhs[k >> 24], 1);
    }
    __syncthreads();
    if (t < NB) {
        bD[t] = lhd[t] ? atomicAdd(&cd[t], lhd[t]) : 0;
        bS[t] = lhs[t] ? atomicAdd(&cs[t], lhs[t]) : 0;
        lhd[t] = 0; lhs[t] = 0;
    }
    __syncthreads();
    for (int e = e0 + t; e < e1; e += 1024) {
        uint32_t k = keys[e];
        float w = ew[e];
        int db = (k >> 8) & 0xff;
        int sb = k >> 24;
        int rd = atomicAdd(&lhd[db], 1);
        uint2 rec;
        rec.x = k;
        rec.y = __float_as_uint(w);
        bdw[bD[db] + rd] = rec;
        int rs = atomicAdd(&lhs[sb], 1);
        __half hw = __float2half(w);
        bs[bS[sb] + rs] = ((uint32_t)*(uint16_t*)&hw << 16) | ((k >> 16) & 0xffu);
    }
}

// ---------------- Kernel C: consume bins -> ninfo (4-batch MLP) ---
__launch_bounds__(1024)
__global__ void k_consume(const uint2* __restrict__ bdw, const uint32_t* __restrict__ bs,
                          const int* __restrict__ offd, const int* __restrict__ offs,
                          const float* __restrict__ x, float* __restrict__ ninfo, int N) {
    __shared__ float accx[PR][6];   // xs0..xs4, cnt
    __shared__ float accd[PR];      // deg
    int t = threadIdx.x;
    int b = blockIdx.x;
    int base = b * PR;
    uint32_t pr = (uint32_t)min(PR, N - base);

    for (int k = t; k < PR * 6; k += 1024) (&accx[0][0])[k] = 0.f;
    for (int k = t; k < PR; k += 1024) accd[k] = 0.f;
    __syncthreads();

    int r0 = offd[b], r1 = offd[b + 1];
    for (int rb = r0 + t; rb < r1; rb += 4096) {
        // batch-load up to 4 records + gathers (independent, overlapped)
        bool vld[4];
        uint2 rec[4];
        #pragma unroll
        for (int u = 0; u < 4; u++) {
            int rr = rb + u * 1024;
            vld[u] = rr < r1;
            if (vld[u]) rec[u] = bdw[rr];
        }
        float xv[4][5];
        #pragma unroll
        for (int u = 0; u < 4; u++) {
            if (vld[u]) {
                const float* xp = x + (size_t)(rec[u].x >> 16) * 5;
                xv[u][0] = xp[0]; xv[u][1] = xp[1]; xv[u][2] = xp[2];
                xv[u][3] = xp[3]; xv[u][4] = xp[4];
            }
        }
        #pragma unroll
        for (int u = 0; u < 4; u++) {
            if (vld[u]) {
                uint32_t dl = rec[u].x & 0xffu;
                atomicAdd(&accx[dl][0], xv[u][0]);
                atomicAdd(&accx[dl][1], xv[u][1]);
                atomicAdd(&accx[dl][2], xv[u][2]);
                atomicAdd(&accx[dl][3], xv[u][3]);
                atomicAdd(&accx[dl][4], xv[u][4]);
                atomicAdd(&accx[dl][5], 1.0f);
            }
        }
    }
    int s0 = offs[b], s1 = offs[b + 1];
    for (int rb = s0 + t; rb < s1; rb += 4096) {
        bool vld[4];
        uint32_t kk[4];
        #pragma unroll
        for (int u = 0; u < 4; u++) {
            int rr = rb + u * 1024;
            vld[u] = rr < s1;
            if (vld[u]) kk[u] = bs[rr];
        }
        #pragma unroll
        for (int u = 0; u < 4; u++) {
            if (vld[u]) {
                uint16_t hw = (uint16_t)(kk[u] >> 16);
                atomicAdd(&accd[kk[u] & 0xffu], __half2float(*(__half*)&hw));
            }
        }
    }
    __syncthreads();

    for (uint32_t n = t; n < pr; n += 1024) {
        float dg = accd[n];
        float dis = (dg > 0.f) ? rsqrtf(fmaxf(dg, 1e-30f)) : 0.f;
        float* o = ninfo + (size_t)(base + n) * 8;
        *(float4*)(o + 0) = make_float4(accx[n][0], accx[n][1], accx[n][2], accx[n][3]);
        *(float4*)(o + 4) = make_float4(accx[n][4], accx[n][5], dg, dis);
    }
}

// ---------------- Kernel B: fused node phase + MFMA pooled --------
// node phase: 32 threads/node (sub = t&31, cols sub+32j), weights in LDS.
// Double-buffered St/Yt: ONE barrier per tile. No min-waves bound (forcing
// 8 waves/EU caps regs at 64 and spills -- round-13 lesson).
#define STRD 40
__launch_bounds__(1024)
__global__ void k_node(const float* __restrict__ x,
                       const float* __restrict__ ninfo,
                       const float* __restrict__ W1p, const float* __restrict__ R1p,
                       const float* __restrict__ b1p,
                       const float* __restrict__ W1e, const float* __restrict__ R1e,
                       const float* __restrict__ b1e,
                       uint32_t* __restrict__ Sq, float* __restrict__ csc,
                       uint32_t* __restrict__ parts,
                       float* __restrict__ scal, int N) {
    __shared__ __half St[2][256 * STRD];  // 2 x 20 KB
    __shared__ __half Yt[2][128 * STRD];  // 2 x 10 KB
    __shared__ float Wc[10][256];         // 10 KB
    __shared__ float bc[256];
    __shared__ float We[10][128];         // 5 KB
    __shared__ float be[128];
    __shared__ float red[16];

    int t = threadIdx.x;
    int wv = t >> 6, lane = t & 63;
    int nl = t >> 5, sub = t & 31;

    for (int k = t; k < 2560; k += 1024) Wc[k >> 8][k & 255] = (k < 1280) ? W1p[k] : R1p[k - 1280];
    for (int k = t; k < 1280; k += 1024) We[k >> 7][k & 127] = (k < 640) ? W1e[k] : R1e[k - 640];
    if (t < 256) bc[t] = b1p[t];
    if (t < 128) be[t] = b1e[t];
    __syncthreads();

    f32x4 acc[8];
    #pragma unroll
    for (int ft = 0; ft < 8; ft++) acc[ft] = (f32x4){0.f, 0.f, 0.f, 0.f};
    float ssq = 0.f;
    int p = 0;

    int ntiles = (N + 31) >> 5;
    for (int tile = blockIdx.x; tile < ntiles; tile += (int)gridDim.x) {
        int i = tile * 32 + nl;
        if (i < N) {
            const float4* ni = (const float4*)(ninfo + (size_t)i * 8);
            float4 plo = ni[0];
            float4 phi = ni[1];
            float dg = phi.z;
            float dis = phi.w;
            float inv_dn = 1.0f / fmaxf(phi.y, 1.0f);
            float z[10];
            z[0] = plo.x * inv_dn; z[1] = plo.y * inv_dn; z[2] = plo.z * inv_dn;
            z[3] = plo.w * inv_dn; z[4] = phi.x * inv_dn;
            const float* xp = x + (size_t)i * 5;
            z[5] = xp[0]; z[6] = xp[1]; z[7] = xp[2]; z[8] = xp[3]; z[9] = xp[4];
            float m[8];
            #pragma unroll
            for (int j = 0; j < 8; j++) {
                int c = sub + 32 * j;
                float v = bc[c];
                #pragma unroll
                for (int d = 0; d < 10; d++) v += z[d] * Wc[d][c];
                m[j] = v;
            }
            float mx = m[0];
            #pragma unroll
            for (int j = 1; j < 8; j++) mx = fmaxf(mx, m[j]);
            #pragma unroll
            for (int o = 16; o > 0; o >>= 1) mx = fmaxf(mx, __shfl_xor(mx, o));
            float ls = 0.f;
            #pragma unroll
            for (int j = 0; j < 8; j++) { m[j] = __expf(m[j] - mx); ls += m[j]; }
            #pragma unroll
            for (int o = 16; o > 0; o >>= 1) ls += __shfl_xor(ls, o);
            float inv_l = 1.0f / ls;
            // quantize e=exp(m-mx) in [0,1] to uint4 with implicit row scale
            uint32_t qp = 0;
            #pragma unroll
            for (int j = 0; j < 8; j++) {
                int q = __float2int_rn(m[j] * 15.f);
                qp |= (uint32_t)min(q, 15) << (4 * j);
            }
            Sq[(size_t)i * 32 + sub] = qp;
            if (sub == 0) csc[i] = dis * inv_l * (1.0f / 15.0f);
            float sq = 0.f;
            #pragma unroll
            for (int j = 0; j < 8; j++) {
                float s = m[j] * inv_l;
                m[j] = s;
                sq += s * s;
                St[p][(sub + 32 * j) * STRD + nl] = __float2half(s);
            }
            if (dg > 0.f) ssq += sq;
            #pragma unroll
            for (int j = 0; j < 4; j++) {
                int f = sub + 32 * j;
                float v = be[f];
                #pragma unroll
                for (int d = 0; d < 10; d++) v += z[d] * We[d][f];
                Yt[p][f * STRD + nl] = __float2half(fmaxf(v, 0.f));
            }
        } else {
            #pragma unroll
            for (int j = 0; j < 8; j++) St[p][(sub + 32 * j) * STRD + nl] = __half(0.f);
            #pragma unroll
            for (int j = 0; j < 4; j++) Yt[p][(sub + 32 * j) * STRD + nl] = __half(0.f);
        }
        __syncthreads();
        // MFMA: wave wv owns c-tile wv (c = wv*16..+16), all 8 f-tiles, K=32.
        {
            int r = lane & 15, kc = lane >> 4;     // k = kc*8 + reg
            uint4 au = *(const uint4*)&St[p][(wv * 16 + r) * STRD + kc * 8];
            f16x8 a = __builtin_bit_cast(f16x8, au);
            #pragma unroll
            for (int ft = 0; ft < 8; ft++) {
                uint4 bu = *(const uint4*)&Yt[p][(ft * 16 + r) * STRD + kc * 8];
                f16x8 b = __builtin_bit_cast(f16x8, bu);
                acc[ft] = __builtin_amdgcn_mfma_f32_16x16x32_f16(a, b, acc[ft], 0, 0, 0);
            }
        }
        p ^= 1;
    }

    // lane-interleaved bf16-pair store: word w = wv*1024 + (ft*2+h)*64 + lane
    {
        uint32_t* pw = parts + (size_t)blockIdx.x * 16384 + wv * 1024 + lane;
        #pragma unroll
        for (int ft = 0; ft < 8; ft++) {
            __hip_bfloat162 h0, h1;
            h0.x = __float2bfloat16(acc[ft][0]);
            h0.y = __float2bfloat16(acc[ft][1]);
            h1.x = __float2bfloat16(acc[ft][2]);
            h1.y = __float2bfloat16(acc[ft][3]);
            pw[(ft * 2) * 64]     = *(uint32_t*)&h0;
            pw[(ft * 2 + 1) * 64] = *(uint32_t*)&h1;
        }
    }

    #pragma unroll
    for (int o = 32; o > 0; o >>= 1) ssq += __shfl_xor(ssq, o);
    if (lane == 0) red[wv] = ssq;
    __syncthreads();
    if (t == 0) {
        float s = 0.f;
        #pragma unroll
        for (int w2 = 0; w2 < 16; w2++) s += red[w2];
        atomicAdd(&scal[0], s);
    }
}

// ---------------- Kernel B2: reduce partials (depermute) ----------
__global__ void k_reduce(const uint32_t* __restrict__ parts,
                         float* __restrict__ pooled, int nparts) {
    int w = blockIdx.x * blockDim.x + threadIdx.x;  // 16384 total
    float s0 = 0.f, s1 = 0.f;
    #pragma unroll 4
    for (int q = 0; q < nparts; q++) {
        uint32_t v = parts[(size_t)q * 16384 + w];
        __hip_bfloat162 h = *(__hip_bfloat162*)&v;
        s0 += __bfloat162float(h.x);
        s1 += __bfloat162float(h.y);
    }
    int lane = w & 63, idx = (w >> 6) & 15, wv = w >> 10;
    int ft = idx >> 1, h = idx & 1;
    int c = wv * 16 + ((lane >> 4) & 3) * 4 + 2 * h;
    int f = ft * 16 + (lane & 15);
    pooled[c * 128 + f] = s0;
    pooled[(c + 1) * 128 + f] = s1;
}

// ---------------- Kernel R: per-edge regularizer (uint4 dot) ------
// 2 lanes/edge (64B of each row), 32 edges/wave in flight.
// XCD-chunked block swizzle for dst-row L2 locality.
__launch_bounds__(256)
__global__ void k_edge_reg(const uint2* __restrict__ bdw,
                           const uint32_t* __restrict__ Sq, const float* __restrict__ csc,
                           float* __restrict__ scal, int E) {
    __shared__ float red[4];
    int t = threadIdx.x;
    int lane = t & 63;
    int sub = lane & 1;
    int grp = lane >> 1;
    int wv = t >> 6;
    int nblocks = (int)gridDim.x;
    int bid = (int)blockIdx.x;
    int swz = (bid & 7) * (nblocks >> 3) + (bid >> 3);   // nblocks % 8 == 0
    int gw = swz * (blockDim.x >> 6) + wv;
    int nwaves = nblocks * (blockDim.x >> 6);

    float acc = 0.f;
    for (int base = gw * 32; base < E; base += nwaves * 32) {
        int e = base + grp;
        int idot = 0;
        float sc = 0.f;
        if (e < E) {
            uint2 rec = bdw[e];
            uint32_t k = rec.x;
            int s = (int)(k >> 16);
            int d = (int)(k & 0xffffu);
            const uint4* pa = (const uint4*)(Sq + (size_t)s * 32) + sub * 4;
            const uint4* pb = (const uint4*)(Sq + (size_t)d * 32) + sub * 4;
            #pragma unroll
            for (int q = 0; q < 4; q++) {
                uint4 A = pa[q];
                uint4 B = pb[q];
                idot = udot8(A.x, B.x, idot);
                idot = udot8(A.y, B.y, idot);
                idot = udot8(A.z, B.z, idot);
                idot = udot8(A.w, B.w, idot);
            }
            sc = __uint_as_float(rec.y) * csc[s] * csc[d];
        }
        idot += __shfl_xor(idot, 1);
        if (sub == 0) acc += sc * (float)idot;
    }

    #pragma unroll
    for (int o = 32; o > 0; o >>= 1) acc += __shfl_xor(acc, o);
    if (lane == 0) red[wv] = acc;
    __syncthreads();
    if (t == 0) atomicAdd(&scal[1], red[0] + red[1] + red[2] + red[3]);
}

// ---------------- Kernel D1: y2 column sums -----------------------
__launch_bounds__(256)
__global__ void k_pool2(const float* __restrict__ pooled,
                        const float* __restrict__ W2e, const float* __restrict__ R2e,
                        const float* __restrict__ b2e, float* __restrict__ g) {
    __shared__ float mh[128];
    __shared__ float prow[128];
    int t = threadIdx.x;
    int c = blockIdx.x;
    if (t < 128) {
        float s = 0.f;
        for (int cc = 0; cc < 256; cc++) s += pooled[cc * 128 + t];
        mh[t] = s * (1.0f / 256.0f);
        prow[t] = pooled[c * 128 + t];
    }
    __syncthreads();
    float v = b2e[t];
    for (int k = 0; k < 128; k++)
        v += mh[k] * W2e[k * 256 + t] + prow[k] * R2e[k * 256 + t];
    v = fmaxf(v, 0.f);
    atomicAdd(&g[t], v);
}

// ---------------- Kernel D2: final MLP + output -------------------
__launch_bounds__(256)
__global__ void k_final(const float* __restrict__ g,
                        const float* __restrict__ Wl1, const float* __restrict__ bl1,
                        const float* __restrict__ Wl2, const float* __restrict__ bl2,
                        const float* __restrict__ scal, float* __restrict__ out, int N) {
    __shared__ float gs[256];
    __shared__ float h1[256];
    __shared__ float lg[10];
    int t = threadIdx.x;
    gs[t] = g[t];
    __syncthreads();
    float v = bl1[t];
    for (int k = 0; k < 256; k++) v += gs[k] * Wl1[k * 256 + t];
    h1[t] = fmaxf(v, 0.f);
    __syncthreads();
    if (t < 10) {
        float s = bl2[t];
        for (int k = 0; k < 256; k++) s += h1[k] * Wl2[k * 10 + t];
        lg[t] = s;
    }
    __syncthreads();
    if (t == 0) {
        float mx = lg[0];
        for (int j = 1; j < 10; j++) mx = fmaxf(mx, lg[j]);
        float ls = 0.f;
        for (int j = 0; j < 10; j++) ls += __expf(lg[j] - mx);
        float lse = mx + logf(ls);
        for (int j = 0; j < 10; j++) out[j] = lg[j] - lse;
        out[10] = (scal[0] - scal[1]) / (float)N;
    }
}

extern "C" void kernel_launch(void* const* d_in, const int* in_sizes, int n_in,
                              void* d_out, int out_size, void* d_ws, size_t ws_size,
                              hipStream_t stream) {
    const float* x   = (const float*)d_in[0];
    const int*   ei  = (const int*)d_in[1];
    const float* ew  = (const float*)d_in[2];
    const float* W1p = (const float*)d_in[3];
    const float* R1p = (const float*)d_in[4];
    const float* b1p = (const float*)d_in[5];
    const float* W1e = (const float*)d_in[6];
    const float* R1e = (const float*)d_in[7];
    const float* b1e = (const float*)d_in[8];
    // d_in[9..11] = W2p,R2p,b2p : dead (softmax over size-1 axis == 1)
    const float* W2e = (const float*)d_in[12];
    const float* R2e = (const float*)d_in[13];
    const float* b2e = (const float*)d_in[14];
    const float* Wl1 = (const float*)d_in[15];
    const float* bl1 = (const float*)d_in[16];
    const float* Wl2 = (const float*)d_in[17];
    const float* bl2 = (const float*)d_in[18];
    float* out = (float*)d_out;

    int N = in_sizes[0] / 5;
    int E = in_sizes[1] / 2;
    int NB = (N + PR - 1) / PR;

    uint32_t* ws = (uint32_t*)d_ws;
    size_t off = 0;
    float* g    = (float*)(ws + off); off += 256;
    float* scal = (float*)(ws + off); off += 2;
    int* hpriv  = (int*)(ws + off); off += (size_t)NHIST * 512;
    int* offd = (int*)(ws + off); off += NBMAX + 1;
    int* offs = (int*)(ws + off); off += NBMAX + 1;
    int* cd   = (int*)(ws + off); off += NBMAX;
    int* cs   = (int*)(ws + off); off += NBMAX;
    off = (off + 3) & ~(size_t)3;                  // 16B align
    float* ninfo = (float*)(ws + off); off += (size_t)N * 8;
    float* csc   = (float*)(ws + off); off += (size_t)N;
    uint32_t* keys = ws + off; off += (size_t)E;
    off = (off + 1) & ~(size_t)1;                  // 8B align
    uint2* bdw = (uint2*)(ws + off); off += (size_t)E * 2;
    uint32_t* bs = ws + off; off += (size_t)E;
    off = (off + 3) & ~(size_t)3;
    uint32_t* Sq = ws + off; off += (size_t)N * 32;
    float* pooled = (float*)(ws + off); off += 32768;
    size_t avail = (ws_size / 4 > off) ? (ws_size / 4 - off) : 0;
    int nparts = (int)(avail / 16384);
    if (nparts > 256) nparts = 256;
    if (nparts < 1) nparts = 1;
    uint32_t* parts = ws + off;

    k_hist<<<NHIST, 1024, 0, stream>>>(ei, keys, hpriv, E);
    k_prefix<<<1, NBMAX, 0, stream>>>(hpriv, offd, offs, cd, cs, g, scal, NB);
    k_scatter<<<(E + SCH - 1) / SCH, 1024, 0, stream>>>(keys, ew, cd, cs, bdw, bs, E, NB);
    k_consume<<<NB, 1024, 0, stream>>>(bdw, bs, offd, offs, x, ninfo, N);
    k_node<<<nparts, 1024, 0, stream>>>(x, ninfo, W1p, R1p, b1p,
                                        W1e, R1e, b1e, Sq, csc, parts, scal, N);
    k_reduce<<<64, 256, 0, stream>>>(parts, pooled, nparts);
    k_edge_reg<<<2048, 256, 0, stream>>>(bdw, Sq, csc, scal, E);
    k_pool2<<<256, 256, 0, stream>>>(pooled, W2e, R2e, b2e, g);
    k_final<<<1, 256, 0, stream>>>(g, Wl1, bl1, Wl2, bl2, scal, out, N);
}